// Round 28
// baseline (205.876 us; speedup 1.0000x reference)
//
#include <hip/hip_runtime.h>
#include <hip/hip_bf16.h>

#define BB   4
#define NN   10000
#define EE   160000
#define FIN  256
#define HH   8
#define FO   32
#define CC   256            // H*FO
#define BN   40000          // B*N
#define BE   640000         // B*E
#define RLEN 64             // CSR row = 64 ints (256B): [0]=cnt, [1..63]=slots
#define CAP  63             // max slots per node (P(Poisson16 > 63) ~ 1e-20)

#define XCVT 5000           // x cvt blocks
#define WCVT 32             // W cvt blocks
#define ZB   157            // cnt-zero blocks (40000 nodes / 256)
#define WBB  8              // w_src/w_trg build blocks (one per head)
#define GMB  626            // gemm blocks (313 row-tiles x 2 col-tiles)
#define CLB  625            // claim blocks (4 edges/thread)
#define SCB  1250           // score blocks (32 nodes x 8 heads)
// k_main grid = 2501; role = blk & 3 (0: gemm, 1: claim, 2|3: score)

typedef __attribute__((ext_vector_type(8))) __bf16 bf16x8;
typedef __attribute__((ext_vector_type(4))) float  f32x4;

__device__ __forceinline__ float bf2f(unsigned short u) {
    unsigned int v = ((unsigned int)u) << 16;
    return __uint_as_float(v);
}
__device__ __forceinline__ unsigned short f2bf(float f) {
    unsigned int u = __float_as_uint(f);
    u += 0x7fffu + ((u >> 16) & 1u);   // round-to-nearest-even
    return (unsigned short)(u >> 16);
}

__device__ __forceinline__ void cvt8(const float* __restrict__ src,
                                     unsigned short* __restrict__ dst, int i)
{
    const float4* s = (const float4*)src + (size_t)i * 2;
    float4 v0 = s[0], v1 = s[1];
    float f[8] = {v0.x, v0.y, v0.z, v0.w, v1.x, v1.y, v1.z, v1.w};
    union { unsigned short u[8]; uint4 q; } o;
#pragma unroll
    for (int j = 0; j < 8; ++j) o.u[j] = f2bf(f[j]);
    ((uint4*)dst)[i] = o.q;
}

// ---------------------------------------------------------------------------
// K1: prep — cvt x->xb || cvt W->wb || zero per-row cnt || build w rows.
// Slots need no zeroing (value-guarded by cnt).
// ---------------------------------------------------------------------------
__global__ __launch_bounds__(256) void k_prep(
    const float* __restrict__ x, const float* __restrict__ Wm,
    const float* __restrict__ a_src, const float* __restrict__ a_trg,
    unsigned short* __restrict__ xb, unsigned short* __restrict__ wb,
    int* __restrict__ esrc, float* __restrict__ wsrcg,
    float* __restrict__ wtrgg)
{
    int blk = blockIdx.x, t = threadIdx.x;
    if (blk < XCVT) {
        cvt8(x, xb, blk * 256 + t);
    } else if (blk < XCVT + WCVT) {
        cvt8(Wm, wb, (blk - XCVT) * 256 + t);
    } else if (blk < XCVT + WCVT + ZB) {
        int node = (blk - XCVT - WCVT) * 256 + t;
        if (node < BN) esrc[(size_t)node * RLEN] = 0;   // cnt = 0
    } else {
        // w_src[h,k] = sum_f a_src[h*32+f] * W[(h*32+f)*256 + k]
        int h = blk - XCVT - WCVT - ZB;              // 0..7
        int k = t;                                   // 0..255
        float s = 0.f, tg = 0.f;
#pragma unroll
        for (int f = 0; f < FO; ++f) {
            float w = Wm[(size_t)(h * FO + f) * FIN + k];
            s  += a_src[h * FO + f] * w;
            tg += a_trg[h * FO + f] * w;
        }
        wsrcg[h * FIN + k] = s;
        wtrgg[h * FIN + k] = tg;
    }
}

// ---------------------------------------------------------------------------
// K2: main — three independent paths, ROLE-INTERLEAVED (blk & 3):
//   role 0: proj = xb @ wb^T (MFMA 128x128, global_load_lds, XOR swizzle)
//   role 1: edge claim: p = atomicAdd(&row[0],1); row[1+p] = src|maskbit.
//           Counter and slots share one 256B row: the atomic warms the
//           line, ~60% of slot stores (p<=14) hit it -> far fewer random
//           sectors than the split deg/esrc layout (R24: claim was
//           random-BW-bound at ~1.8 TB/s). Slots are 4-byte (R25 lesson).
//   role 2|3: scores ssrc/strg = xb . w_src/w_trg (LDS, stride-257)
// ---------------------------------------------------------------------------
__global__ __launch_bounds__(256) void k_main(
    const unsigned short* __restrict__ xb, const unsigned short* __restrict__ wb,
    unsigned short* __restrict__ proj, const int* __restrict__ ei,
    const float* __restrict__ mask, int* __restrict__ esrc,
    const float* __restrict__ wsrcg, const float* __restrict__ wtrgg,
    float* __restrict__ ssrc, float* __restrict__ strg)
{
    __shared__ alignas(16) unsigned char smem[32768];
    const int t = threadIdx.x;
    const int blk = blockIdx.x;
    const int role = blk & 3;
    const int rid  = blk >> 2;

    if (role >= 2) {
        // ---- score path: sid in [0, SCB)
        int sid = rid * 2 + (role - 2);
        float* ws = (float*)smem;                    // [8][257]
        float* wt = ws + 8 * 257;                    // [8][257]
        for (int i = t; i < 8 * FIN; i += 256) {
            int hh = i >> 8, kk = i & 255;
            ws[hh * 257 + kk] = wsrcg[i];
            wt[hh * 257 + kk] = wtrgg[i];
        }
        __syncthreads();
        int node = sid * 32 + (t >> 3);
        int h    = t & 7;
        const uint4* xr = (const uint4*)(xb + (size_t)node * FIN);
        const float* pw = ws + h * 257;
        const float* pt = wt + h * 257;
        float vs = 0.f, vt = 0.f;
#pragma unroll
        for (int i = 0; i < 32; ++i) {
            uint4 q = xr[i];
            unsigned int v[4] = {q.x, q.y, q.z, q.w};
#pragma unroll
            for (int j = 0; j < 4; ++j) {
                float lo = __uint_as_float(v[j] << 16);
                float hi = __uint_as_float(v[j] & 0xffff0000u);
                int c = i * 8 + j * 2;
                vs += lo * pw[c] + hi * pw[c + 1];
                vt += lo * pt[c] + hi * pt[c + 1];
            }
        }
        ssrc[(size_t)node * HH + h] = vs;
        strg[(size_t)node * HH + h] = vt;
        return;
    }

    if (role == 1) {
        // ---- claim path: 4 edges/thread, one atomic + slot store per edge
        int i = rid * 256 + t;                       // [0, BE/4)
        int e0 = i * 4;
        int b  = e0 / EE;                            // EE%4==0 -> uniform
        int le = e0 - b * EE;
        const int* eb = ei + (size_t)b * 2 * EE;
        int4   sq = *(const int4*)(eb + le);
        int4   tq = *(const int4*)(eb + EE + le);
        float4 mq = *(const float4*)(mask + e0);
        int base = b * NN;

        int* r0 = esrc + (size_t)(tq.x + base) * RLEN;
        int* r1 = esrc + (size_t)(tq.y + base) * RLEN;
        int* r2 = esrc + (size_t)(tq.z + base) * RLEN;
        int* r3 = esrc + (size_t)(tq.w + base) * RLEN;
        int p0 = atomicAdd(r0, 1);
        int p1 = atomicAdd(r1, 1);
        int p2 = atomicAdd(r2, 1);
        int p3 = atomicAdd(r3, 1);
        if (p0 < CAP) r0[1 + p0] = (sq.x + base) | (mq.x > 0.f ? 0 : (int)0x80000000);
        if (p1 < CAP) r1[1 + p1] = (sq.y + base) | (mq.y > 0.f ? 0 : (int)0x80000000);
        if (p2 < CAP) r2[1 + p2] = (sq.z + base) | (mq.z > 0.f ? 0 : (int)0x80000000);
        if (p3 < CAP) r3[1 + p3] = (sq.w + base) | (mq.w > 0.f ? 0 : (int)0x80000000);
        return;
    }

    // ---- gemm path: gid in [0, GMB), 128x128 tile, global_load_lds staging
    unsigned short* As = (unsigned short*)smem;          // [128*64]
    unsigned short* Bs = (unsigned short*)(smem + 16384);// [128*64]
    const int lane = t & 63;
    const int wid  = t >> 6;
    const int wr   = wid >> 1, wc = wid & 1;
    const int bm   = rid >> 1;
    const int bn   = rid & 1;
    const int row0 = bm * 128, col0 = bn * 128;

    const int srow = t >> 3;            // 0..31
    const int scol = (t & 7) * 8;

    f32x4 acc[4][4] = {};

    for (int kt = 0; kt < 4; ++kt) {
        const int k0 = kt * 64;
#pragma unroll
        for (int p = 0; p < 4; ++p) {
            int tr = p * 32 + srow;                       // tile row 0..127
            int cg = scol ^ ((tr & 7) << 3);              // inv-swizzled col
            int gra = row0 + tr; if (gra > BN - 1) gra = BN - 1;  // M-tail
            const unsigned short* ga = xb + (size_t)gra * FIN + k0 + cg;
            const unsigned short* gb = wb + (size_t)(col0 + tr) * FIN + k0 + cg;
            __builtin_amdgcn_global_load_lds(
                (const __attribute__((address_space(1))) void*)ga,
                (__attribute__((address_space(3))) void*)&As[p * 2048 + t * 8],
                16, 0, 0);
            __builtin_amdgcn_global_load_lds(
                (const __attribute__((address_space(1))) void*)gb,
                (__attribute__((address_space(3))) void*)&Bs[p * 2048 + t * 8],
                16, 0, 0);
        }
        __syncthreads();   // drains vmcnt before any wave reads LDS

#pragma unroll
        for (int kk = 0; kk < 2; ++kk) {
            bf16x8 af[4], bfr[4];
#pragma unroll
            for (int m = 0; m < 4; ++m) {
                int row = wr * 64 + m * 16 + (lane & 15);
                int col = (kk * 32 + (lane >> 4) * 8) ^ ((row & 7) << 3);
                af[m] = *(const bf16x8*)&As[row * 64 + col];
            }
#pragma unroll
            for (int n = 0; n < 4; ++n) {
                int row = wc * 64 + n * 16 + (lane & 15);
                int col = (kk * 32 + (lane >> 4) * 8) ^ ((row & 7) << 3);
                bfr[n] = *(const bf16x8*)&Bs[row * 64 + col];
            }
#pragma unroll
            for (int m = 0; m < 4; ++m)
#pragma unroll
                for (int n = 0; n < 4; ++n)
                    acc[m][n] = __builtin_amdgcn_mfma_f32_16x16x32_bf16(
                        af[m], bfr[n], acc[m][n], 0, 0, 0);
        }
        __syncthreads();
    }

    const int rbase = row0 + wr * 64 + (lane >> 4) * 4;
    const int cbase = col0 + wc * 64 + (lane & 15);
#pragma unroll
    for (int m = 0; m < 4; ++m)
#pragma unroll
        for (int n = 0; n < 4; ++n)
#pragma unroll
            for (int j = 0; j < 4; ++j) {
                int r = rbase + m * 16 + j;
                int c = cbase + n * 16;
                if (r < BN) proj[(size_t)r * CC + c] = f2bf(acc[m][n][j]);
            }
}

// ---------------------------------------------------------------------------
// K3: gather — one wave per node; cnt = row[0] (broadcast), slots row[1+l]
// loaded once into registers (lane l <- slot l); per-group lookups via
// __shfl. Only the ssrc gather stays on the latency chain (prefetched one
// group ahead).
// ---------------------------------------------------------------------------
__global__ __launch_bounds__(256) void k_gather(
    const int* __restrict__ esrc, const float* __restrict__ ssrc,
    const float* __restrict__ strg, const unsigned short* __restrict__ proj,
    const float* __restrict__ bias, float* __restrict__ out)
{
    int gid  = blockIdx.x * 256 + threadIdx.x;
    int node = gid >> 6;
    int lane = gid & 63;
    if (node >= BN) return;
    int h  = lane >> 3;
    int el = lane & 7;
    int hb = lane & 56;
    float st = strg[(size_t)node * HH + h];
    const int* row = esrc + (size_t)node * RLEN;
    int cnt = row[0]; if (cnt > CAP) cnt = CAP;

    int sv = (lane < cnt) ? row[1 + lane] : (int)0x80000000;

    const char* projc = (const char*)proj;
    const unsigned lb = lane * 8u;               // lane byte offset in row

    float acc0 = 0.f, acc1 = 0.f, acc2 = 0.f, acc3 = 0.f, deno = 0.f;

    int  svo = __shfl(sv, el);
    float f  = ssrc[(size_t)(svo & 0x7fffffff) * HH + h];

    const int ng = (cnt + 7) >> 3;               // groups of 8 edges
    for (int g = 0; g < ng; ++g) {
        int  svn = __shfl(sv, ((g + 1) * 8 + el) & 63);
        float fn = ssrc[(size_t)(svn & 0x7fffffff) * HH + h];

        float c = f + st;
        c = c > 0.f ? c : 0.2f * c;              // leaky_relu(0.2)
        float ex = (svo >= 0) ? __expf(c) : 0.f; // invalid/masked -> 0
        deno += ex;                               // own-lane edge only

#pragma unroll
        for (int e = 0; e < 8; ++e) {
            float ee = __shfl(ex, e | hb);        // (edge e, this head)
            int   se = __shfl(sv, g * 8 + e) & 0x7fffffff;
            ushort4 q = *(const ushort4*)(projc + (((unsigned)se << 9) + lb));
            acc0 += bf2f(q.x) * ee;
            acc1 += bf2f(q.y) * ee;
            acc2 += bf2f(q.z) * ee;
            acc3 += bf2f(q.w) * ee;
        }
        svo = svn; f = fn;
    }

#pragma unroll
    for (int off = 1; off < 8; off <<= 1) deno += __shfl_xor(deno, off);

    float inv = 1.f / (deno + 1e-16f);
    float4 bv = ((const float4*)bias)[lane];
    float o0 = acc0 * inv + bv.x, o1 = acc1 * inv + bv.y;
    float o2 = acc2 * inv + bv.z, o3 = acc3 * inv + bv.w;
    o0 = o0 > 0.f ? o0 : __expf(o0) - 1.f;
    o1 = o1 > 0.f ? o1 : __expf(o1) - 1.f;
    o2 = o2 > 0.f ? o2 : __expf(o2) - 1.f;
    o3 = o3 > 0.f ? o3 : __expf(o3) - 1.f;
    ((float4*)(out + (size_t)node * CC))[lane] = make_float4(o0, o1, o2, o3);
}

// ---------------------------------------------------------------------------
extern "C" void kernel_launch(void* const* d_in, const int* in_sizes, int n_in,
                              void* d_out, int out_size, void* d_ws, size_t ws_size,
                              hipStream_t stream)
{
    const float* x     = (const float*)d_in[0];
    const int*   ei    = (const int*)  d_in[1];
    const float* mask  = (const float*)d_in[2];
    const float* Wm    = (const float*)d_in[3];
    const float* a_src = (const float*)d_in[4];
    const float* a_trg = (const float*)d_in[5];
    const float* bias  = (const float*)d_in[6];
    float* out = (float*)d_out;

    char* ws = (char*)d_ws;
    size_t off = 0;
    unsigned short* xb = (unsigned short*)(ws + off); off += (size_t)BN * FIN * 2; // 20.48 MB
    unsigned short* wb = (unsigned short*)(ws + off); off += (size_t)CC * FIN * 2; //  0.13 MB
    unsigned short* proj = (unsigned short*)(ws + off); off += (size_t)BN * CC * 2;// 20.48 MB
    float* ssrc  = (float*)(ws + off); off += (size_t)BN * HH * 4;                 //  1.28 MB
    float* strg  = (float*)(ws + off); off += (size_t)BN * HH * 4;                 //  1.28 MB
    float* wsrcg = (float*)(ws + off); off += (size_t)HH * FIN * 4;                //  8 KB
    float* wtrgg = (float*)(ws + off); off += (size_t)HH * FIN * 4;                //  8 KB
    off = (off + 255) & ~255ull;                                                   //  align rows
    int*   esrc  = (int*)  (ws + off); off += (size_t)BN * RLEN * 4;               // 10.24 MB

    k_prep  <<<XCVT + WCVT + ZB + WBB, 256, 0, stream>>>(
        x, Wm, a_src, a_trg, xb, wb, esrc, wsrcg, wtrgg);
    k_main  <<<GMB + CLB + SCB, 256, 0, stream>>>(
        xb, wb, proj, ei, mask, esrc, wsrcg, wtrgg, ssrc, strg);
    k_gather<<<(BN * 64) / 256, 256, 0, stream>>>(
        esrc, ssrc, strg, proj, bias, out);
}

// Round 29
// 92.502 us; speedup vs baseline: 2.2256x; 2.2256x over previous
//
#include <hip/hip_runtime.h>
#include <hip/hip_bf16.h>

#define BB   4
#define NN   10000
#define EE   160000
#define FIN  256
#define HH   8
#define FO   32
#define CC   256            // H*FO
#define BN   40000          // B*N
#define BE   640000         // B*E
#define CAP  48             // CSR row capacity (P(Poisson16 > 48) ~ 1e-9/node)
#define DStr 16             // deg stride: one counter per 64B line (kills
                            // cross-XCD per-line atomic serialization)

#define XCVT 5000           // x cvt blocks
#define WCVT 32             // W cvt blocks
#define DZB  625            // deg-zero blocks (BN*DStr ints = 160000 uint4)
#define WBB  8              // w_src/w_trg build blocks (one per head)
#define GMB  626            // gemm blocks (313 row-tiles x 2 col-tiles)
#define CLB  625            // claim blocks (4 edges/thread)
#define SCB  1250           // score blocks (32 nodes x 8 heads)
// k_main grid = 2501; role = blk & 3 (0: gemm, 1: claim, 2|3: score)
// NOTE (R28): do NOT fuse the counter into the slot row — atomic+store on
// one line resurrects cross-XCD ping-pong (93 -> 206 us). Keep split arrays.

typedef __attribute__((ext_vector_type(8))) __bf16 bf16x8;
typedef __attribute__((ext_vector_type(4))) float  f32x4;

__device__ __forceinline__ float bf2f(unsigned short u) {
    unsigned int v = ((unsigned int)u) << 16;
    return __uint_as_float(v);
}
__device__ __forceinline__ unsigned short f2bf(float f) {
    unsigned int u = __float_as_uint(f);
    u += 0x7fffu + ((u >> 16) & 1u);   // round-to-nearest-even
    return (unsigned short)(u >> 16);
}

__device__ __forceinline__ void cvt8(const float* __restrict__ src,
                                     unsigned short* __restrict__ dst, int i)
{
    const float4* s = (const float4*)src + (size_t)i * 2;
    float4 v0 = s[0], v1 = s[1];
    float f[8] = {v0.x, v0.y, v0.z, v0.w, v1.x, v1.y, v1.z, v1.w};
    union { unsigned short u[8]; uint4 q; } o;
#pragma unroll
    for (int j = 0; j < 8; ++j) o.u[j] = f2bf(f[j]);
    ((uint4*)dst)[i] = o.q;
}

// ---------------------------------------------------------------------------
// K1: prep — cvt x->xb || cvt W->wb || zero deg (padded) || build w rows.
// ---------------------------------------------------------------------------
__global__ __launch_bounds__(256) void k_prep(
    const float* __restrict__ x, const float* __restrict__ Wm,
    const float* __restrict__ a_src, const float* __restrict__ a_trg,
    unsigned short* __restrict__ xb, unsigned short* __restrict__ wb,
    int* __restrict__ deg, float* __restrict__ wsrcg,
    float* __restrict__ wtrgg)
{
    int blk = blockIdx.x, t = threadIdx.x;
    if (blk < XCVT) {
        cvt8(x, xb, blk * 256 + t);
    } else if (blk < XCVT + WCVT) {
        cvt8(Wm, wb, (blk - XCVT) * 256 + t);
    } else if (blk < XCVT + WCVT + DZB) {
        int i = (blk - XCVT - WCVT) * 256 + t;       // uint4 index
        if (i < BN * DStr / 4) ((uint4*)deg)[i] = make_uint4(0, 0, 0, 0);
    } else {
        // w_src[h,k] = sum_f a_src[h*32+f] * W[(h*32+f)*256 + k]
        int h = blk - XCVT - WCVT - DZB;             // 0..7
        int k = t;                                   // 0..255
        float s = 0.f, tg = 0.f;
#pragma unroll
        for (int f = 0; f < FO; ++f) {
            float w = Wm[(size_t)(h * FO + f) * FIN + k];
            s  += a_src[h * FO + f] * w;
            tg += a_trg[h * FO + f] * w;
        }
        wsrcg[h * FIN + k] = s;
        wtrgg[h * FIN + k] = tg;
    }
}

// ---------------------------------------------------------------------------
// K2: main — three independent paths, ROLE-INTERLEAVED (blk & 3):
//   role 0: proj = xb @ wb^T (MFMA 128x128, global_load_lds, XOR swizzle)
//   role 1: edge claim: deg[trg*16]++ -> slot esrc[trg*CAP+pos]
//           (padded counters; 4-byte slots — u16 slots race across XCDs, R25)
//   role 2|3: scores ssrc/strg = xb . w_src/w_trg (LDS, stride-257)
// ---------------------------------------------------------------------------
__global__ __launch_bounds__(256) void k_main(
    const unsigned short* __restrict__ xb, const unsigned short* __restrict__ wb,
    unsigned short* __restrict__ proj, const int* __restrict__ ei,
    const float* __restrict__ mask, int* __restrict__ deg,
    int* __restrict__ esrc, const float* __restrict__ wsrcg,
    const float* __restrict__ wtrgg, float* __restrict__ ssrc,
    float* __restrict__ strg)
{
    __shared__ alignas(16) unsigned char smem[32768];
    const int t = threadIdx.x;
    const int blk = blockIdx.x;
    const int role = blk & 3;
    const int rid  = blk >> 2;

    if (role >= 2) {
        // ---- score path: sid in [0, SCB)
        int sid = rid * 2 + (role - 2);
        float* ws = (float*)smem;                    // [8][257]
        float* wt = ws + 8 * 257;                    // [8][257]
        for (int i = t; i < 8 * FIN; i += 256) {
            int hh = i >> 8, kk = i & 255;
            ws[hh * 257 + kk] = wsrcg[i];
            wt[hh * 257 + kk] = wtrgg[i];
        }
        __syncthreads();
        int node = sid * 32 + (t >> 3);
        int h    = t & 7;
        const uint4* xr = (const uint4*)(xb + (size_t)node * FIN);
        const float* pw = ws + h * 257;
        const float* pt = wt + h * 257;
        float vs = 0.f, vt = 0.f;
#pragma unroll
        for (int i = 0; i < 32; ++i) {
            uint4 q = xr[i];
            unsigned int v[4] = {q.x, q.y, q.z, q.w};
#pragma unroll
            for (int j = 0; j < 4; ++j) {
                float lo = __uint_as_float(v[j] << 16);
                float hi = __uint_as_float(v[j] & 0xffff0000u);
                int c = i * 8 + j * 2;
                vs += lo * pw[c] + hi * pw[c + 1];
                vt += lo * pt[c] + hi * pt[c + 1];
            }
        }
        ssrc[(size_t)node * HH + h] = vs;
        strg[(size_t)node * HH + h] = vt;
        return;
    }

    if (role == 1) {
        // ---- claim path: 4 edges/thread, one atomic per edge
        int i = rid * 256 + t;                       // [0, BE/4)
        int e0 = i * 4;
        int b  = e0 / EE;                            // EE%4==0 -> uniform
        int le = e0 - b * EE;
        const int* eb = ei + (size_t)b * 2 * EE;
        int4   sq = *(const int4*)(eb + le);
        int4   tq = *(const int4*)(eb + EE + le);
        float4 mq = *(const float4*)(mask + e0);
        int base = b * NN;

        int t0 = tq.x + base, t1 = tq.y + base, t2 = tq.z + base, t3 = tq.w + base;
        int p0 = atomicAdd(&deg[t0 * DStr], 1);
        int p1 = atomicAdd(&deg[t1 * DStr], 1);
        int p2 = atomicAdd(&deg[t2 * DStr], 1);
        int p3 = atomicAdd(&deg[t3 * DStr], 1);
        if (p0 < CAP) esrc[t0 * CAP + p0] = (sq.x + base) | (mq.x > 0.f ? 0 : (int)0x80000000);
        if (p1 < CAP) esrc[t1 * CAP + p1] = (sq.y + base) | (mq.y > 0.f ? 0 : (int)0x80000000);
        if (p2 < CAP) esrc[t2 * CAP + p2] = (sq.z + base) | (mq.z > 0.f ? 0 : (int)0x80000000);
        if (p3 < CAP) esrc[t3 * CAP + p3] = (sq.w + base) | (mq.w > 0.f ? 0 : (int)0x80000000);
        return;
    }

    // ---- gemm path: gid in [0, GMB), 128x128 tile, global_load_lds staging
    unsigned short* As = (unsigned short*)smem;          // [128*64]
    unsigned short* Bs = (unsigned short*)(smem + 16384);// [128*64]
    const int lane = t & 63;
    const int wid  = t >> 6;
    const int wr   = wid >> 1, wc = wid & 1;
    const int bm   = rid >> 1;
    const int bn   = rid & 1;
    const int row0 = bm * 128, col0 = bn * 128;

    const int srow = t >> 3;            // 0..31
    const int scol = (t & 7) * 8;

    f32x4 acc[4][4] = {};

    for (int kt = 0; kt < 4; ++kt) {
        const int k0 = kt * 64;
#pragma unroll
        for (int p = 0; p < 4; ++p) {
            int tr = p * 32 + srow;                       // tile row 0..127
            int cg = scol ^ ((tr & 7) << 3);              // inv-swizzled col
            int gra = row0 + tr; if (gra > BN - 1) gra = BN - 1;  // M-tail
            const unsigned short* ga = xb + (size_t)gra * FIN + k0 + cg;
            const unsigned short* gb = wb + (size_t)(col0 + tr) * FIN + k0 + cg;
            __builtin_amdgcn_global_load_lds(
                (const __attribute__((address_space(1))) void*)ga,
                (__attribute__((address_space(3))) void*)&As[p * 2048 + t * 8],
                16, 0, 0);
            __builtin_amdgcn_global_load_lds(
                (const __attribute__((address_space(1))) void*)gb,
                (__attribute__((address_space(3))) void*)&Bs[p * 2048 + t * 8],
                16, 0, 0);
        }
        __syncthreads();   // drains vmcnt before any wave reads LDS

#pragma unroll
        for (int kk = 0; kk < 2; ++kk) {
            bf16x8 af[4], bfr[4];
#pragma unroll
            for (int m = 0; m < 4; ++m) {
                int row = wr * 64 + m * 16 + (lane & 15);
                int col = (kk * 32 + (lane >> 4) * 8) ^ ((row & 7) << 3);
                af[m] = *(const bf16x8*)&As[row * 64 + col];
            }
#pragma unroll
            for (int n = 0; n < 4; ++n) {
                int row = wc * 64 + n * 16 + (lane & 15);
                int col = (kk * 32 + (lane >> 4) * 8) ^ ((row & 7) << 3);
                bfr[n] = *(const bf16x8*)&Bs[row * 64 + col];
            }
#pragma unroll
            for (int m = 0; m < 4; ++m)
#pragma unroll
                for (int n = 0; n < 4; ++n)
                    acc[m][n] = __builtin_amdgcn_mfma_f32_16x16x32_bf16(
                        af[m], bfr[n], acc[m][n], 0, 0, 0);
        }
        __syncthreads();
    }

    const int rbase = row0 + wr * 64 + (lane >> 4) * 4;
    const int cbase = col0 + wc * 64 + (lane & 15);
#pragma unroll
    for (int m = 0; m < 4; ++m)
#pragma unroll
        for (int n = 0; n < 4; ++n)
#pragma unroll
            for (int j = 0; j < 4; ++j) {
                int r = rbase + m * 16 + j;
                int c = cbase + n * 16;
                if (r < BN) proj[(size_t)r * CC + c] = f2bf(acc[m][n][j]);
            }
}

// ---------------------------------------------------------------------------
// K3: gather — one wave per node; whole CSR row (<= CAP) loaded once into
// registers (lane l <- slot l); per-group lookups via __shfl. Only the ssrc
// gather stays on the latency chain (prefetched one group ahead).
// ---------------------------------------------------------------------------
__global__ __launch_bounds__(256) void k_gather(
    const int* __restrict__ deg, const int* __restrict__ esrc,
    const float* __restrict__ ssrc, const float* __restrict__ strg,
    const unsigned short* __restrict__ proj, const float* __restrict__ bias,
    float* __restrict__ out)
{
    int gid  = blockIdx.x * 256 + threadIdx.x;
    int node = gid >> 6;
    int lane = gid & 63;
    if (node >= BN) return;
    int h  = lane >> 3;
    int el = lane & 7;
    int hb = lane & 56;
    float st = strg[(size_t)node * HH + h];
    int cnt = deg[node * DStr]; if (cnt > CAP) cnt = CAP;
    const int lo = node * CAP;

    int sv = (lane < cnt) ? esrc[lo + lane] : (int)0x80000000;

    const char* projc = (const char*)proj;
    const unsigned lb = lane * 8u;               // lane byte offset in row

    float acc0 = 0.f, acc1 = 0.f, acc2 = 0.f, acc3 = 0.f, deno = 0.f;

    int  svo = __shfl(sv, el);
    float f  = ssrc[(size_t)(svo & 0x7fffffff) * HH + h];

    const int ng = (cnt + 7) >> 3;               // groups of 8 edges
    for (int g = 0; g < ng; ++g) {
        int  svn = __shfl(sv, ((g + 1) * 8 + el) & 63);
        float fn = ssrc[(size_t)(svn & 0x7fffffff) * HH + h];

        float c = f + st;
        c = c > 0.f ? c : 0.2f * c;              // leaky_relu(0.2)
        float ex = (svo >= 0) ? __expf(c) : 0.f; // invalid/masked -> 0
        deno += ex;                               // own-lane edge only

#pragma unroll
        for (int e = 0; e < 8; ++e) {
            float ee = __shfl(ex, e | hb);        // (edge e, this head)
            int   se = __shfl(sv, g * 8 + e) & 0x7fffffff;
            ushort4 q = *(const ushort4*)(projc + (((unsigned)se << 9) + lb));
            acc0 += bf2f(q.x) * ee;
            acc1 += bf2f(q.y) * ee;
            acc2 += bf2f(q.z) * ee;
            acc3 += bf2f(q.w) * ee;
        }
        svo = svn; f = fn;
    }

#pragma unroll
    for (int off = 1; off < 8; off <<= 1) deno += __shfl_xor(deno, off);

    float inv = 1.f / (deno + 1e-16f);
    float4 bv = ((const float4*)bias)[lane];
    float o0 = acc0 * inv + bv.x, o1 = acc1 * inv + bv.y;
    float o2 = acc2 * inv + bv.z, o3 = acc3 * inv + bv.w;
    o0 = o0 > 0.f ? o0 : __expf(o0) - 1.f;
    o1 = o1 > 0.f ? o1 : __expf(o1) - 1.f;
    o2 = o2 > 0.f ? o2 : __expf(o2) - 1.f;
    o3 = o3 > 0.f ? o3 : __expf(o3) - 1.f;
    ((float4*)(out + (size_t)node * CC))[lane] = make_float4(o0, o1, o2, o3);
}

// ---------------------------------------------------------------------------
extern "C" void kernel_launch(void* const* d_in, const int* in_sizes, int n_in,
                              void* d_out, int out_size, void* d_ws, size_t ws_size,
                              hipStream_t stream)
{
    const float* x     = (const float*)d_in[0];
    const int*   ei    = (const int*)  d_in[1];
    const float* mask  = (const float*)d_in[2];
    const float* Wm    = (const float*)d_in[3];
    const float* a_src = (const float*)d_in[4];
    const float* a_trg = (const float*)d_in[5];
    const float* bias  = (const float*)d_in[6];
    float* out = (float*)d_out;

    char* ws = (char*)d_ws;
    size_t off = 0;
    unsigned short* xb = (unsigned short*)(ws + off); off += (size_t)BN * FIN * 2; // 20.48 MB
    unsigned short* wb = (unsigned short*)(ws + off); off += (size_t)CC * FIN * 2; //  0.13 MB
    unsigned short* proj = (unsigned short*)(ws + off); off += (size_t)BN * CC * 2;// 20.48 MB
    float* ssrc  = (float*)(ws + off); off += (size_t)BN * HH * 4;                 //  1.28 MB
    float* strg  = (float*)(ws + off); off += (size_t)BN * HH * 4;                 //  1.28 MB
    float* wsrcg = (float*)(ws + off); off += (size_t)HH * FIN * 4;                //  8 KB
    float* wtrgg = (float*)(ws + off); off += (size_t)HH * FIN * 4;                //  8 KB
    int*   deg   = (int*)  (ws + off); off += (size_t)BN * DStr * 4;               //  2.56 MB
    int*   esrc  = (int*)  (ws + off); off += (size_t)BN * CAP * 4;                //  7.68 MB

    k_prep  <<<XCVT + WCVT + DZB + WBB, 256, 0, stream>>>(
        x, Wm, a_src, a_trg, xb, wb, deg, wsrcg, wtrgg);
    k_main  <<<GMB + CLB + SCB, 256, 0, stream>>>(
        xb, wb, proj, ei, mask, deg, esrc, wsrcg, wtrgg, ssrc, strg);
    k_gather<<<(BN * 64) / 256, 256, 0, stream>>>(
        deg, esrc, ssrc, strg, proj, bias, out);
}

// Round 30
// 92.425 us; speedup vs baseline: 2.2275x; 1.0008x over previous
//
#include <hip/hip_runtime.h>
#include <hip/hip_bf16.h>

#define BB   4
#define NN   10000
#define EE   160000
#define FIN  256
#define HH   8
#define FO   32
#define CC   256            // H*FO
#define BN   40000          // B*N
#define BE   640000         // B*E
#define CAP  48             // CSR row capacity (P(Poisson16 > 48) ~ 1e-9/node)
#define DStr 16             // deg stride: one counter per 64B line (kills
                            // cross-XCD per-line atomic serialization)

#define XCVT 5000           // x cvt blocks
#define WCVT 32             // W cvt blocks
#define DZB  625            // deg-zero blocks (BN*DStr ints = 160000 uint4)
#define WBB  8              // w_src/w_trg build blocks (one per head)
#define GMB  626            // gemm blocks (313 row-tiles x 2 col-tiles)
#define CLB  625            // claim blocks (4 edges/thread)
#define SCB  1250           // score blocks (32 nodes x 8 heads)
// k_main grid = 2501; role = blk & 3 (0: gemm, 1: claim, 2|3: score)
// NOTE (R28): do NOT fuse the counter into the slot row — atomic+store on
// one line resurrects cross-XCD ping-pong (93 -> 206 us). Keep split arrays.

typedef __attribute__((ext_vector_type(8))) __bf16 bf16x8;
typedef __attribute__((ext_vector_type(4))) float  f32x4;

__device__ __forceinline__ float bf2f(unsigned short u) {
    unsigned int v = ((unsigned int)u) << 16;
    return __uint_as_float(v);
}
__device__ __forceinline__ unsigned short f2bf(float f) {
    unsigned int u = __float_as_uint(f);
    u += 0x7fffu + ((u >> 16) & 1u);   // round-to-nearest-even
    return (unsigned short)(u >> 16);
}

__device__ __forceinline__ void cvt8(const float* __restrict__ src,
                                     unsigned short* __restrict__ dst, int i)
{
    const float4* s = (const float4*)src + (size_t)i * 2;
    float4 v0 = s[0], v1 = s[1];
    float f[8] = {v0.x, v0.y, v0.z, v0.w, v1.x, v1.y, v1.z, v1.w};
    union { unsigned short u[8]; uint4 q; } o;
#pragma unroll
    for (int j = 0; j < 8; ++j) o.u[j] = f2bf(f[j]);
    ((uint4*)dst)[i] = o.q;
}

// ---------------------------------------------------------------------------
// K1: prep — cvt x->xb || cvt W->wb || zero deg (padded) || build w rows.
// ---------------------------------------------------------------------------
__global__ __launch_bounds__(256) void k_prep(
    const float* __restrict__ x, const float* __restrict__ Wm,
    const float* __restrict__ a_src, const float* __restrict__ a_trg,
    unsigned short* __restrict__ xb, unsigned short* __restrict__ wb,
    int* __restrict__ deg, float* __restrict__ wsrcg,
    float* __restrict__ wtrgg)
{
    int blk = blockIdx.x, t = threadIdx.x;
    if (blk < XCVT) {
        cvt8(x, xb, blk * 256 + t);
    } else if (blk < XCVT + WCVT) {
        cvt8(Wm, wb, (blk - XCVT) * 256 + t);
    } else if (blk < XCVT + WCVT + DZB) {
        int i = (blk - XCVT - WCVT) * 256 + t;       // uint4 index
        if (i < BN * DStr / 4) ((uint4*)deg)[i] = make_uint4(0, 0, 0, 0);
    } else {
        // w_src[h,k] = sum_f a_src[h*32+f] * W[(h*32+f)*256 + k]
        int h = blk - XCVT - WCVT - DZB;             // 0..7
        int k = t;                                   // 0..255
        float s = 0.f, tg = 0.f;
#pragma unroll
        for (int f = 0; f < FO; ++f) {
            float w = Wm[(size_t)(h * FO + f) * FIN + k];
            s  += a_src[h * FO + f] * w;
            tg += a_trg[h * FO + f] * w;
        }
        wsrcg[h * FIN + k] = s;
        wtrgg[h * FIN + k] = tg;
    }
}

// ---------------------------------------------------------------------------
// K2: main — three independent paths, ROLE-INTERLEAVED (blk & 3):
//   role 0: proj = xb @ wb^T (MFMA 128x128, global_load_lds, XOR swizzle)
//   role 1: edge claim: deg[trg*16]++ -> slot esrc[trg*CAP+pos]
//           (padded counters; 4-byte slots — u16 slots race across XCDs, R25)
//   role 2|3: scores ssrc/strg = xb . w_src/w_trg (LDS, stride-257)
// ---------------------------------------------------------------------------
__global__ __launch_bounds__(256) void k_main(
    const unsigned short* __restrict__ xb, const unsigned short* __restrict__ wb,
    unsigned short* __restrict__ proj, const int* __restrict__ ei,
    const float* __restrict__ mask, int* __restrict__ deg,
    int* __restrict__ esrc, const float* __restrict__ wsrcg,
    const float* __restrict__ wtrgg, float* __restrict__ ssrc,
    float* __restrict__ strg)
{
    __shared__ alignas(16) unsigned char smem[32768];
    const int t = threadIdx.x;
    const int blk = blockIdx.x;
    const int role = blk & 3;
    const int rid  = blk >> 2;

    if (role >= 2) {
        // ---- score path: sid in [0, SCB)
        int sid = rid * 2 + (role - 2);
        float* ws = (float*)smem;                    // [8][257]
        float* wt = ws + 8 * 257;                    // [8][257]
        for (int i = t; i < 8 * FIN; i += 256) {
            int hh = i >> 8, kk = i & 255;
            ws[hh * 257 + kk] = wsrcg[i];
            wt[hh * 257 + kk] = wtrgg[i];
        }
        __syncthreads();
        int node = sid * 32 + (t >> 3);
        int h    = t & 7;
        const uint4* xr = (const uint4*)(xb + (size_t)node * FIN);
        const float* pw = ws + h * 257;
        const float* pt = wt + h * 257;
        float vs = 0.f, vt = 0.f;
#pragma unroll
        for (int i = 0; i < 32; ++i) {
            uint4 q = xr[i];
            unsigned int v[4] = {q.x, q.y, q.z, q.w};
#pragma unroll
            for (int j = 0; j < 4; ++j) {
                float lo = __uint_as_float(v[j] << 16);
                float hi = __uint_as_float(v[j] & 0xffff0000u);
                int c = i * 8 + j * 2;
                vs += lo * pw[c] + hi * pw[c + 1];
                vt += lo * pt[c] + hi * pt[c + 1];
            }
        }
        ssrc[(size_t)node * HH + h] = vs;
        strg[(size_t)node * HH + h] = vt;
        return;
    }

    if (role == 1) {
        // ---- claim path: 4 edges/thread, one atomic per edge
        int i = rid * 256 + t;                       // [0, BE/4)
        int e0 = i * 4;
        int b  = e0 / EE;                            // EE%4==0 -> uniform
        int le = e0 - b * EE;
        const int* eb = ei + (size_t)b * 2 * EE;
        int4   sq = *(const int4*)(eb + le);
        int4   tq = *(const int4*)(eb + EE + le);
        float4 mq = *(const float4*)(mask + e0);
        int base = b * NN;

        int t0 = tq.x + base, t1 = tq.y + base, t2 = tq.z + base, t3 = tq.w + base;
        int p0 = atomicAdd(&deg[t0 * DStr], 1);
        int p1 = atomicAdd(&deg[t1 * DStr], 1);
        int p2 = atomicAdd(&deg[t2 * DStr], 1);
        int p3 = atomicAdd(&deg[t3 * DStr], 1);
        if (p0 < CAP) esrc[t0 * CAP + p0] = (sq.x + base) | (mq.x > 0.f ? 0 : (int)0x80000000);
        if (p1 < CAP) esrc[t1 * CAP + p1] = (sq.y + base) | (mq.y > 0.f ? 0 : (int)0x80000000);
        if (p2 < CAP) esrc[t2 * CAP + p2] = (sq.z + base) | (mq.z > 0.f ? 0 : (int)0x80000000);
        if (p3 < CAP) esrc[t3 * CAP + p3] = (sq.w + base) | (mq.w > 0.f ? 0 : (int)0x80000000);
        return;
    }

    // ---- gemm path: gid in [0, GMB), 128x128 tile, global_load_lds staging
    unsigned short* As = (unsigned short*)smem;          // [128*64]
    unsigned short* Bs = (unsigned short*)(smem + 16384);// [128*64]
    const int lane = t & 63;
    const int wid  = t >> 6;
    const int wr   = wid >> 1, wc = wid & 1;
    const int bm   = rid >> 1;
    const int bn   = rid & 1;
    const int row0 = bm * 128, col0 = bn * 128;

    const int srow = t >> 3;            // 0..31
    const int scol = (t & 7) * 8;

    f32x4 acc[4][4] = {};

    for (int kt = 0; kt < 4; ++kt) {
        const int k0 = kt * 64;
#pragma unroll
        for (int p = 0; p < 4; ++p) {
            int tr = p * 32 + srow;                       // tile row 0..127
            int cg = scol ^ ((tr & 7) << 3);              // inv-swizzled col
            int gra = row0 + tr; if (gra > BN - 1) gra = BN - 1;  // M-tail
            const unsigned short* ga = xb + (size_t)gra * FIN + k0 + cg;
            const unsigned short* gb = wb + (size_t)(col0 + tr) * FIN + k0 + cg;
            __builtin_amdgcn_global_load_lds(
                (const __attribute__((address_space(1))) void*)ga,
                (__attribute__((address_space(3))) void*)&As[p * 2048 + t * 8],
                16, 0, 0);
            __builtin_amdgcn_global_load_lds(
                (const __attribute__((address_space(1))) void*)gb,
                (__attribute__((address_space(3))) void*)&Bs[p * 2048 + t * 8],
                16, 0, 0);
        }
        __syncthreads();   // drains vmcnt before any wave reads LDS

#pragma unroll
        for (int kk = 0; kk < 2; ++kk) {
            bf16x8 af[4], bfr[4];
#pragma unroll
            for (int m = 0; m < 4; ++m) {
                int row = wr * 64 + m * 16 + (lane & 15);
                int col = (kk * 32 + (lane >> 4) * 8) ^ ((row & 7) << 3);
                af[m] = *(const bf16x8*)&As[row * 64 + col];
            }
#pragma unroll
            for (int n = 0; n < 4; ++n) {
                int row = wc * 64 + n * 16 + (lane & 15);
                int col = (kk * 32 + (lane >> 4) * 8) ^ ((row & 7) << 3);
                bfr[n] = *(const bf16x8*)&Bs[row * 64 + col];
            }
#pragma unroll
            for (int m = 0; m < 4; ++m)
#pragma unroll
                for (int n = 0; n < 4; ++n)
                    acc[m][n] = __builtin_amdgcn_mfma_f32_16x16x32_bf16(
                        af[m], bfr[n], acc[m][n], 0, 0, 0);
        }
        __syncthreads();
    }

    const int rbase = row0 + wr * 64 + (lane >> 4) * 4;
    const int cbase = col0 + wc * 64 + (lane & 15);
#pragma unroll
    for (int m = 0; m < 4; ++m)
#pragma unroll
        for (int n = 0; n < 4; ++n)
#pragma unroll
            for (int j = 0; j < 4; ++j) {
                int r = rbase + m * 16 + j;
                int c = cbase + n * 16;
                if (r < BN) proj[(size_t)r * CC + c] = f2bf(acc[m][n][j]);
            }
}

// ---------------------------------------------------------------------------
// K3: gather — one wave per node; whole CSR row (<= CAP) loaded once into
// registers (lane l <- slot l); per-group lookups via __shfl. Only the ssrc
// gather stays on the latency chain (prefetched one group ahead).
// ---------------------------------------------------------------------------
__global__ __launch_bounds__(256) void k_gather(
    const int* __restrict__ deg, const int* __restrict__ esrc,
    const float* __restrict__ ssrc, const float* __restrict__ strg,
    const unsigned short* __restrict__ proj, const float* __restrict__ bias,
    float* __restrict__ out)
{
    int gid  = blockIdx.x * 256 + threadIdx.x;
    int node = gid >> 6;
    int lane = gid & 63;
    if (node >= BN) return;
    int h  = lane >> 3;
    int el = lane & 7;
    int hb = lane & 56;
    float st = strg[(size_t)node * HH + h];
    int cnt = deg[node * DStr]; if (cnt > CAP) cnt = CAP;
    const int lo = node * CAP;

    int sv = (lane < cnt) ? esrc[lo + lane] : (int)0x80000000;

    const char* projc = (const char*)proj;
    const unsigned lb = lane * 8u;               // lane byte offset in row

    float acc0 = 0.f, acc1 = 0.f, acc2 = 0.f, acc3 = 0.f, deno = 0.f;

    int  svo = __shfl(sv, el);
    float f  = ssrc[(size_t)(svo & 0x7fffffff) * HH + h];

    const int ng = (cnt + 7) >> 3;               // groups of 8 edges
    for (int g = 0; g < ng; ++g) {
        int  svn = __shfl(sv, ((g + 1) * 8 + el) & 63);
        float fn = ssrc[(size_t)(svn & 0x7fffffff) * HH + h];

        float c = f + st;
        c = c > 0.f ? c : 0.2f * c;              // leaky_relu(0.2)
        float ex = (svo >= 0) ? __expf(c) : 0.f; // invalid/masked -> 0
        deno += ex;                               // own-lane edge only

#pragma unroll
        for (int e = 0; e < 8; ++e) {
            float ee = __shfl(ex, e | hb);        // (edge e, this head)
            int   se = __shfl(sv, g * 8 + e) & 0x7fffffff;
            ushort4 q = *(const ushort4*)(projc + (((unsigned)se << 9) + lb));
            acc0 += bf2f(q.x) * ee;
            acc1 += bf2f(q.y) * ee;
            acc2 += bf2f(q.z) * ee;
            acc3 += bf2f(q.w) * ee;
        }
        svo = svn; f = fn;
    }

#pragma unroll
    for (int off = 1; off < 8; off <<= 1) deno += __shfl_xor(deno, off);

    float inv = 1.f / (deno + 1e-16f);
    float4 bv = ((const float4*)bias)[lane];
    float o0 = acc0 * inv + bv.x, o1 = acc1 * inv + bv.y;
    float o2 = acc2 * inv + bv.z, o3 = acc3 * inv + bv.w;
    o0 = o0 > 0.f ? o0 : __expf(o0) - 1.f;
    o1 = o1 > 0.f ? o1 : __expf(o1) - 1.f;
    o2 = o2 > 0.f ? o2 : __expf(o2) - 1.f;
    o3 = o3 > 0.f ? o3 : __expf(o3) - 1.f;
    ((float4*)(out + (size_t)node * CC))[lane] = make_float4(o0, o1, o2, o3);
}

// ---------------------------------------------------------------------------
extern "C" void kernel_launch(void* const* d_in, const int* in_sizes, int n_in,
                              void* d_out, int out_size, void* d_ws, size_t ws_size,
                              hipStream_t stream)
{
    const float* x     = (const float*)d_in[0];
    const int*   ei    = (const int*)  d_in[1];
    const float* mask  = (const float*)d_in[2];
    const float* Wm    = (const float*)d_in[3];
    const float* a_src = (const float*)d_in[4];
    const float* a_trg = (const float*)d_in[5];
    const float* bias  = (const float*)d_in[6];
    float* out = (float*)d_out;

    char* ws = (char*)d_ws;
    size_t off = 0;
    unsigned short* xb = (unsigned short*)(ws + off); off += (size_t)BN * FIN * 2; // 20.48 MB
    unsigned short* wb = (unsigned short*)(ws + off); off += (size_t)CC * FIN * 2; //  0.13 MB
    unsigned short* proj = (unsigned short*)(ws + off); off += (size_t)BN * CC * 2;// 20.48 MB
    float* ssrc  = (float*)(ws + off); off += (size_t)BN * HH * 4;                 //  1.28 MB
    float* strg  = (float*)(ws + off); off += (size_t)BN * HH * 4;                 //  1.28 MB
    float* wsrcg = (float*)(ws + off); off += (size_t)HH * FIN * 4;                //  8 KB
    float* wtrgg = (float*)(ws + off); off += (size_t)HH * FIN * 4;                //  8 KB
    int*   deg   = (int*)  (ws + off); off += (size_t)BN * DStr * 4;               //  2.56 MB
    int*   esrc  = (int*)  (ws + off); off += (size_t)BN * CAP * 4;                //  7.68 MB

    k_prep  <<<XCVT + WCVT + DZB + WBB, 256, 0, stream>>>(
        x, Wm, a_src, a_trg, xb, wb, deg, wsrcg, wtrgg);
    k_main  <<<GMB + CLB + SCB, 256, 0, stream>>>(
        xb, wb, proj, ei, mask, deg, esrc, wsrcg, wtrgg, ssrc, strg);
    k_gather<<<(BN * 64) / 256, 256, 0, stream>>>(
        deg, esrc, ssrc, strg, proj, bias, out);
}